// Round 1
// baseline (1322.573 us; speedup 1.0000x reference)
//
#include <hip/hip_runtime.h>

#define BATCH 32
#define NMAT 1024
#define NBLK 256              // one block per CU -> all co-resident
#define NWAVE 16
#define ROWS_PW 8             // rows per wave; block owns 128 rows of one batch
#define REG_ROWS 5            // E rows held in VGPRs per wave
#define LDS_ROWS 3            // E rows held in LDS per wave (16*3*2KB = 96 KB)
#define N_ITERS 20
#define SHIFT 5.0f            // E stores t' = exp(-10*D + 5); e^5 cancels in t/S

typedef _Float16 h8 __attribute__((ext_vector_type(8)));

__device__ __forceinline__ float wave_allsum(float s) {
#pragma unroll
    for (int off = 1; off < 64; off <<= 1) s += __shfl_xor(s, off, 64);
    return s;
}

__device__ __forceinline__ float4 f4add(float4 a, float4 b) {
    return make_float4(a.x + b.x, a.y + b.y, a.z + b.z, a.w + b.w);
}

// Workspace is poisoned between runs: zero the per-iteration arrival counters.
__global__ void init_ctr(unsigned* __restrict__ ctr) { ctr[threadIdx.x] = 0u; }

// In-block reduction of per-wave column partials.
// acc[k2*8+q] is this lane's partial for column 512*k2 + 8*lane + q.
// Returns this thread's 16-wave total for column == tid.
// All LDS traffic is float4 at 16B/lane stride (conflict-free):
// slot index = [w4][h][lane], h = 2*k2 + (q>>2).
__device__ __forceinline__ float stage_colsum(const float* acc, float4* sbuf,
                                              int wave, int lane, int tid) {
    const int w4 = wave & 3;
    float4 mine[4];
#pragma unroll
    for (int h = 0; h < 4; ++h) {
        const float* a = acc + ((h >> 1) << 3) + ((h & 1) << 2);
        mine[h] = make_float4(a[0], a[1], a[2], a[3]);
    }
    __syncthreads();                      // previous readers of sbuf are done
    if (wave < 4) {
#pragma unroll
        for (int h = 0; h < 4; ++h) sbuf[(w4 << 8) + (h << 6) + lane] = mine[h];
    }
    __syncthreads();
#pragma unroll
    for (int g = 1; g < 4; ++g) {         // 3 serialized add rounds
        if ((wave >> 2) == g) {
#pragma unroll
            for (int h = 0; h < 4; ++h) {
                const int idx = (w4 << 8) + (h << 6) + lane;
                sbuf[idx] = f4add(sbuf[idx], mine[h]);
            }
        }
        __syncthreads();
    }
    const int rem = tid & 511, lt = rem >> 3, ut = rem & 7;
    const int ht = ((tid >> 9) << 1) + (ut >> 2), rt = ut & 3;
    const float* bf = (const float*)sbuf;
    float cs = 0.f;
#pragma unroll
    for (int w = 0; w < 4; ++w) cs += bf[(((w << 8) + (ht << 6) + lt) << 2) + rt];
    return cs;
}

// Device-scope grid barrier: per-iteration counter slot (no reset, no ABA).
// Release add publishes this block's prior global stores (writes back our
// XCD L2); acquire load invalidates caches before post-barrier reads.
__device__ __forceinline__ void grid_barrier(unsigned* c, int tid) {
    __syncthreads();   // all waves drained their vmem (compiler waitcnt) & LDS use
    if (tid == 0) {
        __threadfence();
        __hip_atomic_fetch_add(c, 1u, __ATOMIC_RELEASE, __HIP_MEMORY_SCOPE_AGENT);
        int guard = 0;
        while (__hip_atomic_load(c, __ATOMIC_RELAXED, __HIP_MEMORY_SCOPE_AGENT) < NBLK &&
               guard < (1 << 24)) {       // ~0.5 s bail-out: fail, don't hang
            __builtin_amdgcn_s_sleep(2);
            ++guard;
        }
        (void)__hip_atomic_load(c, __ATOMIC_ACQUIRE, __HIP_MEMORY_SCOPE_AGENT);
    }
    __syncthreads();
}

__global__ void __launch_bounds__(1024)
sinkhorn_persist(const float* __restrict__ D, float* __restrict__ Pg,
                 float* __restrict__ Qg, unsigned* __restrict__ ctr,
                 float* __restrict__ out) {
    __shared__ __align__(16) _Float16 eL[NWAVE * LDS_ROWS][NMAT]; // 96 KB
    __shared__ float4 sbuf[1024];                                 // 16 KB
    __shared__ float4 evb4[NMAT / 4];                             // 4 KB (permuted)
    float* evb = (float*)evb4;

    const int b = blockIdx.x;
    const int bb = b >> 3, slab = b & 7;       // batch, row-slab within batch
    const int tid = threadIdx.x;
    const int wave = tid >> 6, lane = tid & 63;
    const size_t rbase = ((size_t)bb << 10) + (slab << 7) + (wave << 3);

    h8 er[REG_ROWS][2];      // 5 E rows in VGPRs (40 VGPRs)
    float evr[16];           // ev at this lane's 16 columns
    float colacc[16], qacc[16];

#pragma unroll 1
    for (int it = 0; it < N_ITERS; ++it) {
        const bool last = (it == N_ITERS - 1);
#pragma unroll
        for (int q = 0; q < 16; ++q) colacc[q] = 0.f;
        if (last) {
#pragma unroll
            for (int q = 0; q < 16; ++q) qacc[q] = 0.f;
        }

        if (it == 0) {
            // Build phase: read D (only HBM-scale traffic), build fp16 E into
            // regs+LDS, and do iteration 1 (ev == 1) on the fly.
#pragma unroll
            for (int rr = 0; rr < ROWS_PW; ++rr) {
                const float4* D4 = (const float4*)(D + ((rbase + rr) << 10));
                float t[16];
#pragma unroll
                for (int k2 = 0; k2 < 2; ++k2) {
                    const int c = lane + (k2 << 6);
                    float4 d0 = D4[2 * c], d1 = D4[2 * c + 1];
                    float* tv = t + (k2 << 3);
                    tv[0] = __expf(fmaf(d0.x, -10.f, SHIFT));
                    tv[1] = __expf(fmaf(d0.y, -10.f, SHIFT));
                    tv[2] = __expf(fmaf(d0.z, -10.f, SHIFT));
                    tv[3] = __expf(fmaf(d0.w, -10.f, SHIFT));
                    tv[4] = __expf(fmaf(d1.x, -10.f, SHIFT));
                    tv[5] = __expf(fmaf(d1.y, -10.f, SHIFT));
                    tv[6] = __expf(fmaf(d1.z, -10.f, SHIFT));
                    tv[7] = __expf(fmaf(d1.w, -10.f, SHIFT));
                    h8 o;
#pragma unroll
                    for (int q = 0; q < 8; ++q) o[q] = (_Float16)tv[q];
                    if (rr < REG_ROWS) er[rr][k2] = o;
                    else ((h8*)eL[wave * LDS_ROWS + rr - REG_ROWS])[c] = o;
                }
                float s = 0.f;
#pragma unroll
                for (int q = 0; q < 16; ++q) s += t[q];
                s = wave_allsum(s);
                const float rs = __builtin_amdgcn_rcpf(s);
#pragma unroll
                for (int q = 0; q < 16; ++q) colacc[q] = fmaf(t[q], rs, colacc[q]);
            }
        } else {
            // Gather ev for this lane's 16 columns (permuted evb: 16B/lane stride).
            {
#pragma unroll
                for (int h = 0; h < 4; ++h) {
                    float4 e = evb4[(h << 6) + lane];
                    float* ev = evr + ((h >> 1) << 3) + ((h & 1) << 2);
                    ev[0] = e.x; ev[1] = e.y; ev[2] = e.z; ev[3] = e.w;
                }
            }
#pragma unroll
            for (int rr = 0; rr < ROWS_PW; ++rr) {
                h8 h0, h1;
                if (rr < REG_ROWS) { h0 = er[rr][0]; h1 = er[rr][1]; }
                else {
                    const h8* Er = (const h8*)eL[wave * LDS_ROWS + rr - REG_ROWS];
                    h0 = Er[lane]; h1 = Er[lane + 64];
                }
                float t[16];
#pragma unroll
                for (int q = 0; q < 8; ++q) { t[q] = (float)h0[q]; t[8 + q] = (float)h1[q]; }
                float s = 0.f;
#pragma unroll
                for (int q = 0; q < 16; ++q) s = fmaf(t[q], evr[q], s);
                s = wave_allsum(s);
                const float rs = __builtin_amdgcn_rcpf(s);
#pragma unroll
                for (int q = 0; q < 16; ++q) colacc[q] = fmaf(t[q], rs, colacc[q]);
                if (last) {
#pragma unroll
                    for (int q = 0; q < 16; ++q) {
                        const float dd = (SHIFT - __logf(t[q])) * 0.1f;
                        qacc[q] = fmaf(t[q] * dd, rs, qacc[q]);
                    }
                }
            }
        }

        // Block-level column reduction -> one 4 KB partial per block.
        const int par = it & 1;   // parity double-buffer (no 2nd barrier needed)
        const float cs = stage_colsum(colacc, sbuf, wave, lane, tid);
        Pg[((par * NBLK + b) << 10) + tid] = cs;
        if (last) {
            const float qs = stage_colsum(qacc, sbuf, wave, lane, tid);
            Qg[(b << 10) + tid] = qs;
            if (b == 0 && tid == 0) out[0] = 0.f;   // arm final atomics
        }

        grid_barrier(&ctr[it], tid);

        if (!last) {
            // Redundant per-block ev: gather this batch's 8 partials.
            const float* Pb = Pg + ((par * NBLK + (bb << 3)) << 10) + tid;
            float s8 = 0.f;
#pragma unroll
            for (int j = 0; j < 8; ++j) s8 += Pb[j << 10];
            const float evv = 1.0f / s8;
            const int rem = tid & 511, lt = rem >> 3, ut = rem & 7;
            const int ht = ((tid >> 9) << 1) + (ut >> 2), rt = ut & 3;
            evb[(((ht << 6) + lt) << 2) + rt] = evv;
            __syncthreads();               // evb ready for next iteration
        } else if (slab == 0) {
            // loss = mean_b sum_m (sum_j Q[j][m]) / (sum_j P[j][m])
            const float* Pb = Pg + ((par * NBLK + (bb << 3)) << 10) + tid;
            const float* Qb = Qg + (((bb << 3)) << 10) + tid;
            float s8 = 0.f, q8 = 0.f;
#pragma unroll
            for (int j = 0; j < 8; ++j) { s8 += Pb[j << 10]; q8 += Qb[j << 10]; }
            float c = q8 / s8;
            c = wave_allsum(c);
            if (lane == 0) ((float*)sbuf)[wave] = c;
            __syncthreads();
            if (tid == 0) {
                float tot = 0.f;
#pragma unroll
                for (int w = 0; w < NWAVE; ++w) tot += ((float*)sbuf)[w];
                atomicAdd(out, tot * (1.0f / (float)BATCH));
            }
        }
    }
}

extern "C" void kernel_launch(void* const* d_in, const int* in_sizes, int n_in,
                              void* d_out, int out_size, void* d_ws, size_t ws_size,
                              hipStream_t stream) {
    const float* D = (const float*)d_in[0];
    float* out = (float*)d_out;

    unsigned* ctr = (unsigned*)d_ws;                    // 64 slots (zeroed below)
    float* Pg = (float*)((char*)d_ws + 1024);           // [2][256][1024] f32 = 2 MB
    float* Qg = Pg + 2 * NBLK * NMAT;                   // [256][1024] f32 = 1 MB

    init_ctr<<<1, 64, 0, stream>>>(ctr);
    sinkhorn_persist<<<NBLK, NWAVE * 64, 0, stream>>>(D, Pg, Qg, ctr, out);
}

// Round 2
// 1280.448 us; speedup vs baseline: 1.0329x; 1.0329x over previous
//
#include <hip/hip_runtime.h>

#define BATCH 32
#define NMAT 1024
#define NBLK 256              // one block per CU -> all co-resident
#define NWAVE 16
#define ROWS_PW 8             // rows per wave; block owns 128 rows of one batch
#define REG_ROWS 4            // E rows held in VGPRs per wave (32 VGPRs)
#define LDS_ROWS 4            // E rows held in LDS per wave (16*4*2KB = 128 KB)
#define N_ITERS 20
#define SHIFT 5.0f            // E stores t' = exp(-10*D + 5); e^5 cancels in t/S

typedef _Float16 h8 __attribute__((ext_vector_type(8)));

__device__ __forceinline__ float wave_allsum(float s) {
#pragma unroll
    for (int off = 1; off < 64; off <<= 1) s += __shfl_xor(s, off, 64);
    return s;
}

__device__ __forceinline__ float4 f4add(float4 a, float4 b) {
    return make_float4(a.x + b.x, a.y + b.y, a.z + b.z, a.w + b.w);
}

// Workspace is poisoned between runs: zero the per-iteration arrival counters.
__global__ void init_ctr(unsigned* __restrict__ ctr) { ctr[threadIdx.x] = 0u; }

// In-block reduction of per-wave column partials.
// acc[k2*8+q] is this lane's partial for column 512*k2 + 8*lane + q.
// Returns this thread's 16-wave total for column == tid.
// All LDS traffic is float4 at 16B/lane stride (conflict-free):
// slot index = [w4][h][lane], h = 2*k2 + (q>>2).
__device__ __forceinline__ float stage_colsum(const float* acc, float4* sbuf,
                                              int wave, int lane, int tid) {
    const int w4 = wave & 3;
    float4 mine[4];
#pragma unroll
    for (int h = 0; h < 4; ++h) {
        const float* a = acc + ((h >> 1) << 3) + ((h & 1) << 2);
        mine[h] = make_float4(a[0], a[1], a[2], a[3]);
    }
    __syncthreads();                      // previous readers of sbuf are done
    if (wave < 4) {
#pragma unroll
        for (int h = 0; h < 4; ++h) sbuf[(w4 << 8) + (h << 6) + lane] = mine[h];
    }
    __syncthreads();
#pragma unroll
    for (int g = 1; g < 4; ++g) {         // 3 serialized add rounds
        if ((wave >> 2) == g) {
#pragma unroll
            for (int h = 0; h < 4; ++h) {
                const int idx = (w4 << 8) + (h << 6) + lane;
                sbuf[idx] = f4add(sbuf[idx], mine[h]);
            }
        }
        __syncthreads();
    }
    const int rem = tid & 511, lt = rem >> 3, ut = rem & 7;
    const int ht = ((tid >> 9) << 1) + (ut >> 2), rt = ut & 3;
    const float* bf = (const float*)sbuf;
    float cs = 0.f;
#pragma unroll
    for (int w = 0; w < 4; ++w) cs += bf[(((w << 8) + (ht << 6) + lt) << 2) + rt];
    return cs;
}

// Device-scope grid barrier: per-iteration counter slot (no reset, no ABA).
// Release add publishes this block's prior global stores (writes back our
// XCD L2); acquire load invalidates caches before post-barrier reads.
__device__ __forceinline__ void grid_barrier(unsigned* c, int tid) {
    __syncthreads();   // all waves drained their vmem (compiler waitcnt) & LDS use
    if (tid == 0) {
        __threadfence();
        __hip_atomic_fetch_add(c, 1u, __ATOMIC_RELEASE, __HIP_MEMORY_SCOPE_AGENT);
        int guard = 0;
        while (__hip_atomic_load(c, __ATOMIC_RELAXED, __HIP_MEMORY_SCOPE_AGENT) < NBLK &&
               guard < (1 << 24)) {       // ~0.5 s bail-out: fail, don't hang
            __builtin_amdgcn_s_sleep(2);
            ++guard;
        }
        (void)__hip_atomic_load(c, __ATOMIC_ACQUIRE, __HIP_MEMORY_SCOPE_AGENT);
    }
    __syncthreads();
}

// 16 waves/block = 4 waves/EU min -> VGPR cap 128 (was 64 -> massive spills).
__global__ void __launch_bounds__(1024, 4)
sinkhorn_persist(const float* __restrict__ D, float* __restrict__ Pg,
                 float* __restrict__ Qg, unsigned* __restrict__ ctr,
                 float* __restrict__ out) {
    __shared__ __align__(16) _Float16 eL[NWAVE * LDS_ROWS][NMAT]; // 128 KB
    __shared__ float4 sbuf[1024];                                 // 16 KB
    __shared__ float4 evb4[NMAT / 4];                             // 4 KB (permuted)
    float* evb = (float*)evb4;

    const int b = blockIdx.x;
    const int bb = b >> 3, slab = b & 7;       // batch, row-slab within batch
    const int tid = threadIdx.x;
    const int wave = tid >> 6, lane = tid & 63;
    const size_t rbase = ((size_t)bb << 10) + (slab << 7) + (wave << 3);

    h8 er[REG_ROWS][2];      // 4 E rows in VGPRs (32 VGPRs)
    float evr[16];           // ev at this lane's 16 columns
    float colacc[16], qacc[16];

#pragma unroll 1
    for (int it = 0; it < N_ITERS; ++it) {
        const bool last = (it == N_ITERS - 1);
#pragma unroll
        for (int q = 0; q < 16; ++q) colacc[q] = 0.f;
        if (last) {
#pragma unroll
            for (int q = 0; q < 16; ++q) qacc[q] = 0.f;
        }

        if (it == 0) {
            // Build phase: read D (only HBM-scale traffic), build fp16 E into
            // regs+LDS, and do iteration 1 (ev == 1) on the fly.
#pragma unroll
            for (int rr = 0; rr < ROWS_PW; ++rr) {
                const float4* D4 = (const float4*)(D + ((rbase + rr) << 10));
                float t[16];
#pragma unroll
                for (int k2 = 0; k2 < 2; ++k2) {
                    const int c = lane + (k2 << 6);
                    float4 d0 = D4[2 * c], d1 = D4[2 * c + 1];
                    float* tv = t + (k2 << 3);
                    tv[0] = __expf(fmaf(d0.x, -10.f, SHIFT));
                    tv[1] = __expf(fmaf(d0.y, -10.f, SHIFT));
                    tv[2] = __expf(fmaf(d0.z, -10.f, SHIFT));
                    tv[3] = __expf(fmaf(d0.w, -10.f, SHIFT));
                    tv[4] = __expf(fmaf(d1.x, -10.f, SHIFT));
                    tv[5] = __expf(fmaf(d1.y, -10.f, SHIFT));
                    tv[6] = __expf(fmaf(d1.z, -10.f, SHIFT));
                    tv[7] = __expf(fmaf(d1.w, -10.f, SHIFT));
                    h8 o;
#pragma unroll
                    for (int q = 0; q < 8; ++q) o[q] = (_Float16)tv[q];
                    if (rr < REG_ROWS) er[rr][k2] = o;
                    else ((h8*)eL[wave * LDS_ROWS + rr - REG_ROWS])[c] = o;
                }
                float s = 0.f;
#pragma unroll
                for (int q = 0; q < 16; ++q) s += t[q];
                s = wave_allsum(s);
                const float rs = __builtin_amdgcn_rcpf(s);
#pragma unroll
                for (int q = 0; q < 16; ++q) colacc[q] = fmaf(t[q], rs, colacc[q]);
            }
        } else {
            // Gather ev for this lane's 16 columns (permuted evb: 16B/lane stride).
            {
#pragma unroll
                for (int h = 0; h < 4; ++h) {
                    float4 e = evb4[(h << 6) + lane];
                    float* ev = evr + ((h >> 1) << 3) + ((h & 1) << 2);
                    ev[0] = e.x; ev[1] = e.y; ev[2] = e.z; ev[3] = e.w;
                }
            }
#pragma unroll
            for (int rr = 0; rr < ROWS_PW; ++rr) {
                h8 h0, h1;
                if (rr < REG_ROWS) { h0 = er[rr][0]; h1 = er[rr][1]; }
                else {
                    const h8* Er = (const h8*)eL[wave * LDS_ROWS + rr - REG_ROWS];
                    h0 = Er[lane]; h1 = Er[lane + 64];
                }
                float t[16];
#pragma unroll
                for (int q = 0; q < 8; ++q) { t[q] = (float)h0[q]; t[8 + q] = (float)h1[q]; }
                float s = 0.f;
#pragma unroll
                for (int q = 0; q < 16; ++q) s = fmaf(t[q], evr[q], s);
                s = wave_allsum(s);
                const float rs = __builtin_amdgcn_rcpf(s);
#pragma unroll
                for (int q = 0; q < 16; ++q) colacc[q] = fmaf(t[q], rs, colacc[q]);
                if (last) {
#pragma unroll
                    for (int q = 0; q < 16; ++q) {
                        const float dd = (SHIFT - __logf(t[q])) * 0.1f;
                        qacc[q] = fmaf(t[q] * dd, rs, qacc[q]);
                    }
                }
            }
        }

        // Block-level column reduction -> one 4 KB partial per block.
        const int par = it & 1;   // parity double-buffer (no 2nd barrier needed)
        const float cs = stage_colsum(colacc, sbuf, wave, lane, tid);
        Pg[((par * NBLK + b) << 10) + tid] = cs;
        if (last) {
            const float qs = stage_colsum(qacc, sbuf, wave, lane, tid);
            Qg[(b << 10) + tid] = qs;
            if (b == 0 && tid == 0) out[0] = 0.f;   // arm final atomics
        }

        grid_barrier(&ctr[it], tid);

        if (!last) {
            // Redundant per-block ev: gather this batch's 8 partials.
            const float* Pb = Pg + ((par * NBLK + (bb << 3)) << 10) + tid;
            float s8 = 0.f;
#pragma unroll
            for (int j = 0; j < 8; ++j) s8 += Pb[j << 10];
            const float evv = 1.0f / s8;
            const int rem = tid & 511, lt = rem >> 3, ut = rem & 7;
            const int ht = ((tid >> 9) << 1) + (ut >> 2), rt = ut & 3;
            evb[(((ht << 6) + lt) << 2) + rt] = evv;
            __syncthreads();               // evb ready for next iteration
        } else if (slab == 0) {
            // loss = mean_b sum_m (sum_j Q[j][m]) / (sum_j P[j][m])
            const float* Pb = Pg + ((par * NBLK + (bb << 3)) << 10) + tid;
            const float* Qb = Qg + (((bb << 3)) << 10) + tid;
            float s8 = 0.f, q8 = 0.f;
#pragma unroll
            for (int j = 0; j < 8; ++j) { s8 += Pb[j << 10]; q8 += Qb[j << 10]; }
            float c = q8 / s8;
            c = wave_allsum(c);
            if (lane == 0) ((float*)sbuf)[wave] = c;
            __syncthreads();
            if (tid == 0) {
                float tot = 0.f;
#pragma unroll
                for (int w = 0; w < NWAVE; ++w) tot += ((float*)sbuf)[w];
                atomicAdd(out, tot * (1.0f / (float)BATCH));
            }
        }
    }
}

extern "C" void kernel_launch(void* const* d_in, const int* in_sizes, int n_in,
                              void* d_out, int out_size, void* d_ws, size_t ws_size,
                              hipStream_t stream) {
    const float* D = (const float*)d_in[0];
    float* out = (float*)d_out;

    unsigned* ctr = (unsigned*)d_ws;                    // 64 slots (zeroed below)
    float* Pg = (float*)((char*)d_ws + 1024);           // [2][256][1024] f32 = 2 MB
    float* Qg = Pg + 2 * NBLK * NMAT;                   // [256][1024] f32 = 1 MB

    init_ctr<<<1, 64, 0, stream>>>(ctr);
    sinkhorn_persist<<<NBLK, NWAVE * 64, 0, stream>>>(D, Pg, Qg, ctr, out);
}

// Round 3
// 1248.018 us; speedup vs baseline: 1.0597x; 1.0260x over previous
//
#include <hip/hip_runtime.h>

#define BATCH 32
#define NMAT 1024
#define NBLK 256              // one block per CU -> all co-resident
#define NWAVE 16
#define ROWS_PW 8             // rows per wave; block owns 128 rows of one batch
#define REG_ROWS 4            // E rows held in VGPRs per wave (32 VGPRs)
#define LDS_ROWS 4            // E rows held in LDS per wave (16*4*2KB = 128 KB)
#define N_ITERS 20
#define SHIFT 5.0f            // E stores t' = exp(-10*D + 5); e^5 cancels in t/S

typedef _Float16 h8 __attribute__((ext_vector_type(8)));
typedef float    f8 __attribute__((ext_vector_type(8)));

__device__ __forceinline__ float wave_allsum(float s) {
#pragma unroll
    for (int off = 1; off < 64; off <<= 1) s += __shfl_xor(s, off, 64);
    return s;
}

__device__ __forceinline__ float4 f4add(float4 a, float4 b) {
    return make_float4(a.x + b.x, a.y + b.y, a.z + b.z, a.w + b.w);
}

// Workspace is poisoned between runs: zero the per-iteration arrival counters.
__global__ void init_ctr(unsigned* __restrict__ ctr) { ctr[threadIdx.x] = 0u; }

// In-block reduction of per-wave column partials. a0/a1 by VALUE (no local
// arrays anywhere -> nothing for SROA to miss). a0[q] is column 8*lane+q,
// a1[q] is column 512+8*lane+q. Returns 16-wave total for column == tid.
// All LDS traffic is float4 at 16B/lane stride (conflict-free).
__device__ __forceinline__ float stage_colsum(f8 a0, f8 a1, float4* sbuf,
                                              int wave, int lane, int tid) {
    const int w4 = wave & 3;
    const float4 m0 = make_float4(a0[0], a0[1], a0[2], a0[3]);
    const float4 m1 = make_float4(a0[4], a0[5], a0[6], a0[7]);
    const float4 m2 = make_float4(a1[0], a1[1], a1[2], a1[3]);
    const float4 m3 = make_float4(a1[4], a1[5], a1[6], a1[7]);
    __syncthreads();                      // previous readers of sbuf are done
    const int i0 = (w4 << 8) + lane;
    if (wave < 4) {
        sbuf[i0]       = m0;
        sbuf[i0 + 64]  = m1;
        sbuf[i0 + 128] = m2;
        sbuf[i0 + 192] = m3;
    }
    __syncthreads();
#pragma unroll
    for (int g = 1; g < 4; ++g) {         // 3 serialized add rounds
        if ((wave >> 2) == g) {
            sbuf[i0]       = f4add(sbuf[i0],       m0);
            sbuf[i0 + 64]  = f4add(sbuf[i0 + 64],  m1);
            sbuf[i0 + 128] = f4add(sbuf[i0 + 128], m2);
            sbuf[i0 + 192] = f4add(sbuf[i0 + 192], m3);
        }
        __syncthreads();
    }
    const int rem = tid & 511, lt = rem >> 3, ut = rem & 7;
    const int ht = ((tid >> 9) << 1) + (ut >> 2), rt = ut & 3;
    const float* bf = (const float*)sbuf;
    float cs = 0.f;
#pragma unroll
    for (int w = 0; w < 4; ++w) cs += bf[(((w << 8) + (ht << 6) + lt) << 2) + rt];
    return cs;
}

// Device-scope grid barrier: per-iteration counter slot (no reset, no ABA).
__device__ __forceinline__ void grid_barrier(unsigned* c, int tid) {
    __syncthreads();
    if (tid == 0) {
        __threadfence();
        __hip_atomic_fetch_add(c, 1u, __ATOMIC_RELEASE, __HIP_MEMORY_SCOPE_AGENT);
        int guard = 0;
        while (__hip_atomic_load(c, __ATOMIC_RELAXED, __HIP_MEMORY_SCOPE_AGENT) < NBLK &&
               guard < (1 << 24)) {       // ~0.5 s bail-out: fail, don't hang
            __builtin_amdgcn_s_sleep(2);
            ++guard;
        }
        (void)__hip_atomic_load(c, __ATOMIC_ACQUIRE, __HIP_MEMORY_SCOPE_AGENT);
    }
    __syncthreads();
}

// Build one E row from D: fp16 row into STORE target, row-sum partials into ca.
#define BUILD_ROW(RR, STORE)                                                     \
    {                                                                            \
        const float4* D4 = (const float4*)(D + ((rbase + (RR)) << 10));          \
        const float4 d0 = D4[2 * lane],        d1 = D4[2 * lane + 1];            \
        const float4 d2 = D4[2 * (lane + 64)], d3 = D4[2 * (lane + 64) + 1];     \
        f8 t0, t1;                                                               \
        t0[0] = __expf(fmaf(d0.x, -10.f, SHIFT));                                \
        t0[1] = __expf(fmaf(d0.y, -10.f, SHIFT));                                \
        t0[2] = __expf(fmaf(d0.z, -10.f, SHIFT));                                \
        t0[3] = __expf(fmaf(d0.w, -10.f, SHIFT));                                \
        t0[4] = __expf(fmaf(d1.x, -10.f, SHIFT));                                \
        t0[5] = __expf(fmaf(d1.y, -10.f, SHIFT));                                \
        t0[6] = __expf(fmaf(d1.z, -10.f, SHIFT));                                \
        t0[7] = __expf(fmaf(d1.w, -10.f, SHIFT));                                \
        t1[0] = __expf(fmaf(d2.x, -10.f, SHIFT));                                \
        t1[1] = __expf(fmaf(d2.y, -10.f, SHIFT));                                \
        t1[2] = __expf(fmaf(d2.z, -10.f, SHIFT));                                \
        t1[3] = __expf(fmaf(d2.w, -10.f, SHIFT));                                \
        t1[4] = __expf(fmaf(d3.x, -10.f, SHIFT));                                \
        t1[5] = __expf(fmaf(d3.y, -10.f, SHIFT));                                \
        t1[6] = __expf(fmaf(d3.z, -10.f, SHIFT));                                \
        t1[7] = __expf(fmaf(d3.w, -10.f, SHIFT));                                \
        h8 o0, o1;                                                               \
        _Pragma("unroll")                                                        \
        for (int q = 0; q < 8; ++q) { o0[q] = (_Float16)t0[q]; o1[q] = (_Float16)t1[q]; } \
        STORE;                                                                   \
        float s = 0.f;                                                           \
        _Pragma("unroll") for (int q = 0; q < 8; ++q) s += t0[q];                \
        _Pragma("unroll") for (int q = 0; q < 8; ++q) s += t1[q];                \
        s = wave_allsum(s);                                                      \
        const float rs = __builtin_amdgcn_rcpf(s);                               \
        _Pragma("unroll") for (int q = 0; q < 8; ++q) ca0[q] = fmaf(t0[q], rs, ca0[q]); \
        _Pragma("unroll") for (int q = 0; q < 8; ++q) ca1[q] = fmaf(t1[q], rs, ca1[q]); \
    }

// One Sinkhorn row step: s = sum(t*ev); ca += t/s; (last) qa += t*d/s.
#define ITER_ROW(H0, H1)                                                         \
    {                                                                            \
        const h8 h0 = (H0), h1 = (H1);                                           \
        f8 t0, t1;                                                               \
        _Pragma("unroll")                                                        \
        for (int q = 0; q < 8; ++q) { t0[q] = (float)h0[q]; t1[q] = (float)h1[q]; } \
        float s = 0.f;                                                           \
        _Pragma("unroll") for (int q = 0; q < 8; ++q) s = fmaf(t0[q], ev0[q], s); \
        _Pragma("unroll") for (int q = 0; q < 8; ++q) s = fmaf(t1[q], ev1[q], s); \
        s = wave_allsum(s);                                                      \
        const float rs = __builtin_amdgcn_rcpf(s);                               \
        _Pragma("unroll") for (int q = 0; q < 8; ++q) ca0[q] = fmaf(t0[q], rs, ca0[q]); \
        _Pragma("unroll") for (int q = 0; q < 8; ++q) ca1[q] = fmaf(t1[q], rs, ca1[q]); \
        if (last) {                                                              \
            _Pragma("unroll")                                                    \
            for (int q = 0; q < 8; ++q) {                                        \
                const float dd = (SHIFT - __logf(t0[q])) * 0.1f;                 \
                qa0[q] = fmaf(t0[q] * dd, rs, qa0[q]);                           \
            }                                                                    \
            _Pragma("unroll")                                                    \
            for (int q = 0; q < 8; ++q) {                                        \
                const float dd = (SHIFT - __logf(t1[q])) * 0.1f;                 \
                qa1[q] = fmaf(t1[q] * dd, rs, qa1[q]);                           \
            }                                                                    \
        }                                                                        \
    }

#define LDS_ROW_PTR(K) ((const h8*)eL[wave * LDS_ROWS + (K)])

__global__ void __launch_bounds__(1024, 4)
sinkhorn_persist(const float* __restrict__ D, float* __restrict__ Pg,
                 float* __restrict__ Qg, unsigned* __restrict__ ctr,
                 float* __restrict__ out) {
    __shared__ __align__(16) _Float16 eL[NWAVE * LDS_ROWS][NMAT]; // 128 KB
    __shared__ float4 sbuf[1024];                                 // 16 KB
    __shared__ float4 evb4[NMAT / 4];                             // 4 KB (permuted)
    float* evb = (float*)evb4;

    const int b = blockIdx.x;
    const int bb = b >> 3, slab = b & 7;       // batch, row-slab within batch
    const int tid = threadIdx.x;
    const int wave = tid >> 6, lane = tid & 63;
    const size_t rbase = ((size_t)bb << 10) + (slab << 7) + (wave << 3);

    // All per-lane state as NAMED vector variables (no arrays -> no scratch).
    h8 e0a, e0b, e1a, e1b, e2a, e2b, e3a, e3b;   // 4 E rows in regs (32 VGPRs)
    f8 ev0, ev1;                                 // ev at this lane's 16 columns
    f8 ca0, ca1, qa0, qa1;

#pragma unroll 1
    for (int it = 0; it < N_ITERS; ++it) {
        const bool last = (it == N_ITERS - 1);
#pragma unroll
        for (int q = 0; q < 8; ++q) { ca0[q] = 0.f; ca1[q] = 0.f; }
        if (last) {
#pragma unroll
            for (int q = 0; q < 8; ++q) { qa0[q] = 0.f; qa1[q] = 0.f; }
        }

        if (it == 0) {
            // Build phase: read D (only HBM-scale traffic), build fp16 E into
            // regs+LDS, and do iteration 1 (ev == 1) on the fly.
            BUILD_ROW(0, e0a = o0; e0b = o1)
            BUILD_ROW(1, e1a = o0; e1b = o1)
            BUILD_ROW(2, e2a = o0; e2b = o1)
            BUILD_ROW(3, e3a = o0; e3b = o1)
            BUILD_ROW(4, { h8* Er = (h8*)eL[wave * LDS_ROWS + 0]; Er[lane] = o0; Er[lane + 64] = o1; })
            BUILD_ROW(5, { h8* Er = (h8*)eL[wave * LDS_ROWS + 1]; Er[lane] = o0; Er[lane + 64] = o1; })
            BUILD_ROW(6, { h8* Er = (h8*)eL[wave * LDS_ROWS + 2]; Er[lane] = o0; Er[lane + 64] = o1; })
            BUILD_ROW(7, { h8* Er = (h8*)eL[wave * LDS_ROWS + 3]; Er[lane] = o0; Er[lane + 64] = o1; })
        } else {
            // Gather ev for this lane's 16 columns (permuted evb: 16B/lane stride).
            {
                const float4 g0 = evb4[lane];
                const float4 g1 = evb4[64 + lane];
                const float4 g2 = evb4[128 + lane];
                const float4 g3 = evb4[192 + lane];
                ev0[0] = g0.x; ev0[1] = g0.y; ev0[2] = g0.z; ev0[3] = g0.w;
                ev0[4] = g1.x; ev0[5] = g1.y; ev0[6] = g1.z; ev0[7] = g1.w;
                ev1[0] = g2.x; ev1[1] = g2.y; ev1[2] = g2.z; ev1[3] = g2.w;
                ev1[4] = g3.x; ev1[5] = g3.y; ev1[6] = g3.z; ev1[7] = g3.w;
            }
            ITER_ROW(e0a, e0b)
            ITER_ROW(e1a, e1b)
            ITER_ROW(e2a, e2b)
            ITER_ROW(e3a, e3b)
            ITER_ROW(LDS_ROW_PTR(0)[lane], LDS_ROW_PTR(0)[lane + 64])
            ITER_ROW(LDS_ROW_PTR(1)[lane], LDS_ROW_PTR(1)[lane + 64])
            ITER_ROW(LDS_ROW_PTR(2)[lane], LDS_ROW_PTR(2)[lane + 64])
            ITER_ROW(LDS_ROW_PTR(3)[lane], LDS_ROW_PTR(3)[lane + 64])
        }

        // Block-level column reduction -> one 4 KB partial per block.
        const int par = it & 1;   // parity double-buffer (no 2nd barrier needed)
        const float cs = stage_colsum(ca0, ca1, sbuf, wave, lane, tid);
        Pg[((par * NBLK + b) << 10) + tid] = cs;
        if (last) {
            const float qs = stage_colsum(qa0, qa1, sbuf, wave, lane, tid);
            Qg[(b << 10) + tid] = qs;
            if (b == 0 && tid == 0) out[0] = 0.f;   // arm final atomics
        }

        grid_barrier(&ctr[it], tid);

        if (!last) {
            // Redundant per-block ev: gather this batch's 8 partials.
            const float* Pb = Pg + ((par * NBLK + (bb << 3)) << 10) + tid;
            float s8 = 0.f;
#pragma unroll
            for (int j = 0; j < 8; ++j) s8 += Pb[j << 10];
            const float evv = 1.0f / s8;
            const int rem = tid & 511, lt = rem >> 3, ut = rem & 7;
            const int ht = ((tid >> 9) << 1) + (ut >> 2), rt = ut & 3;
            evb[(((ht << 6) + lt) << 2) + rt] = evv;
            __syncthreads();               // evb ready for next iteration
        } else if (slab == 0) {
            // loss = mean_b sum_m (sum_j Q[j][m]) / (sum_j P[j][m])
            const float* Pb = Pg + ((par * NBLK + (bb << 3)) << 10) + tid;
            const float* Qb = Qg + (((bb << 3)) << 10) + tid;
            float s8 = 0.f, q8 = 0.f;
#pragma unroll
            for (int j = 0; j < 8; ++j) { s8 += Pb[j << 10]; q8 += Qb[j << 10]; }
            float c = q8 / s8;
            c = wave_allsum(c);
            if (lane == 0) ((float*)sbuf)[wave] = c;
            __syncthreads();
            if (tid == 0) {
                float tot = 0.f;
#pragma unroll
                for (int w = 0; w < NWAVE; ++w) tot += ((float*)sbuf)[w];
                atomicAdd(out, tot * (1.0f / (float)BATCH));
            }
        }
    }
}

extern "C" void kernel_launch(void* const* d_in, const int* in_sizes, int n_in,
                              void* d_out, int out_size, void* d_ws, size_t ws_size,
                              hipStream_t stream) {
    const float* D = (const float*)d_in[0];
    float* out = (float*)d_out;

    unsigned* ctr = (unsigned*)d_ws;                    // 64 slots (zeroed below)
    float* Pg = (float*)((char*)d_ws + 1024);           // [2][256][1024] f32 = 2 MB
    float* Qg = Pg + 2 * NBLK * NMAT;                   // [256][1024] f32 = 1 MB

    init_ctr<<<1, 64, 0, stream>>>(ctr);
    sinkhorn_persist<<<NBLK, NWAVE * 64, 0, stream>>>(D, Pg, Qg, ctr, out);
}

// Round 4
// 1246.002 us; speedup vs baseline: 1.0615x; 1.0016x over previous
//
#include <hip/hip_runtime.h>

#define BATCH 32
#define NMAT 1024
#define NBLK 256              // one block per CU -> all co-resident
#define NWAVE 16
#define ROWS_PW 8             // rows per wave; block owns 128 rows of one batch
#define REG_ROWS 4            // E rows held in VGPRs per wave (32 VGPRs)
#define LDS_ROWS 4            // E rows held in LDS per wave (16*4*2KB = 128 KB)
#define N_ITERS 20
#define SHIFT 5.0f            // E stores t' = exp(-10*D + 5); e^5 cancels in t/S

typedef _Float16 h8 __attribute__((ext_vector_type(8)));
typedef float    f8 __attribute__((ext_vector_type(8)));

__device__ __forceinline__ float wave_allsum(float s) {
#pragma unroll
    for (int off = 1; off < 64; off <<= 1) s += __shfl_xor(s, off, 64);
    return s;
}

__device__ __forceinline__ float4 f4add(float4 a, float4 b) {
    return make_float4(a.x + b.x, a.y + b.y, a.z + b.z, a.w + b.w);
}

// Workspace is poisoned between runs: zero the per-iteration arrival counters.
__global__ void init_ctr(unsigned* __restrict__ ctr) { ctr[threadIdx.x] = 0u; }

// In-block reduction of per-wave column partials. a0/a1 by VALUE (no local
// arrays anywhere -> nothing for SROA to miss). a0[q] is column 8*lane+q,
// a1[q] is column 512+8*lane+q. Returns 16-wave total for column == tid.
// All LDS traffic is float4 at 16B/lane stride (conflict-free).
__device__ __forceinline__ float stage_colsum(f8 a0, f8 a1, float4* sbuf,
                                              int wave, int lane, int tid) {
    const int w4 = wave & 3;
    const float4 m0 = make_float4(a0[0], a0[1], a0[2], a0[3]);
    const float4 m1 = make_float4(a0[4], a0[5], a0[6], a0[7]);
    const float4 m2 = make_float4(a1[0], a1[1], a1[2], a1[3]);
    const float4 m3 = make_float4(a1[4], a1[5], a1[6], a1[7]);
    __syncthreads();                      // previous readers of sbuf are done
    const int i0 = (w4 << 8) + lane;
    if (wave < 4) {
        sbuf[i0]       = m0;
        sbuf[i0 + 64]  = m1;
        sbuf[i0 + 128] = m2;
        sbuf[i0 + 192] = m3;
    }
    __syncthreads();
#pragma unroll
    for (int g = 1; g < 4; ++g) {         // 3 serialized add rounds
        if ((wave >> 2) == g) {
            sbuf[i0]       = f4add(sbuf[i0],       m0);
            sbuf[i0 + 64]  = f4add(sbuf[i0 + 64],  m1);
            sbuf[i0 + 128] = f4add(sbuf[i0 + 128], m2);
            sbuf[i0 + 192] = f4add(sbuf[i0 + 192], m3);
        }
        __syncthreads();
    }
    const int rem = tid & 511, lt = rem >> 3, ut = rem & 7;
    const int ht = ((tid >> 9) << 1) + (ut >> 2), rt = ut & 3;
    const float* bf = (const float*)sbuf;
    float cs = 0.f;
#pragma unroll
    for (int w = 0; w < 4; ++w) cs += bf[(((w << 8) + (ht << 6) + lt) << 2) + rt];
    return cs;
}

// Device-scope grid barrier: per-iteration counter slot (no reset, no ABA).
__device__ __forceinline__ void grid_barrier(unsigned* c, int tid) {
    __syncthreads();
    if (tid == 0) {
        __threadfence();
        __hip_atomic_fetch_add(c, 1u, __ATOMIC_RELEASE, __HIP_MEMORY_SCOPE_AGENT);
        int guard = 0;
        while (__hip_atomic_load(c, __ATOMIC_RELAXED, __HIP_MEMORY_SCOPE_AGENT) < NBLK &&
               guard < (1 << 24)) {       // ~0.5 s bail-out: fail, don't hang
            __builtin_amdgcn_s_sleep(2);
            ++guard;
        }
        (void)__hip_atomic_load(c, __ATOMIC_ACQUIRE, __HIP_MEMORY_SCOPE_AGENT);
    }
    __syncthreads();
}

// Build one E row from D: fp16 row into STORE target, row-sum partials into ca.
#define BUILD_ROW(RR, STORE)                                                     \
    {                                                                            \
        const float4* D4 = (const float4*)(D + ((rbase + (RR)) << 10));          \
        const float4 d0 = D4[2 * lane],        d1 = D4[2 * lane + 1];            \
        const float4 d2 = D4[2 * (lane + 64)], d3 = D4[2 * (lane + 64) + 1];     \
        f8 t0, t1;                                                               \
        t0[0] = __expf(fmaf(d0.x, -10.f, SHIFT));                                \
        t0[1] = __expf(fmaf(d0.y, -10.f, SHIFT));                                \
        t0[2] = __expf(fmaf(d0.z, -10.f, SHIFT));                                \
        t0[3] = __expf(fmaf(d0.w, -10.f, SHIFT));                                \
        t0[4] = __expf(fmaf(d1.x, -10.f, SHIFT));                                \
        t0[5] = __expf(fmaf(d1.y, -10.f, SHIFT));                                \
        t0[6] = __expf(fmaf(d1.z, -10.f, SHIFT));                                \
        t0[7] = __expf(fmaf(d1.w, -10.f, SHIFT));                                \
        t1[0] = __expf(fmaf(d2.x, -10.f, SHIFT));                                \
        t1[1] = __expf(fmaf(d2.y, -10.f, SHIFT));                                \
        t1[2] = __expf(fmaf(d2.z, -10.f, SHIFT));                                \
        t1[3] = __expf(fmaf(d2.w, -10.f, SHIFT));                                \
        t1[4] = __expf(fmaf(d3.x, -10.f, SHIFT));                                \
        t1[5] = __expf(fmaf(d3.y, -10.f, SHIFT));                                \
        t1[6] = __expf(fmaf(d3.z, -10.f, SHIFT));                                \
        t1[7] = __expf(fmaf(d3.w, -10.f, SHIFT));                                \
        h8 o0, o1;                                                               \
        _Pragma("unroll")                                                        \
        for (int q = 0; q < 8; ++q) { o0[q] = (_Float16)t0[q]; o1[q] = (_Float16)t1[q]; } \
        STORE;                                                                   \
        float s = 0.f;                                                           \
        _Pragma("unroll") for (int q = 0; q < 8; ++q) s += t0[q];                \
        _Pragma("unroll") for (int q = 0; q < 8; ++q) s += t1[q];                \
        s = wave_allsum(s);                                                      \
        const float rs = __builtin_amdgcn_rcpf(s);                               \
        _Pragma("unroll") for (int q = 0; q < 8; ++q) ca0[q] = fmaf(t0[q], rs, ca0[q]); \
        _Pragma("unroll") for (int q = 0; q < 8; ++q) ca1[q] = fmaf(t1[q], rs, ca1[q]); \
    }

// One Sinkhorn row step: s = sum(t*ev); ca += t/s; (last) qa += t*d/s.
#define ITER_ROW(H0, H1)                                                         \
    {                                                                            \
        const h8 h0 = (H0), h1 = (H1);                                           \
        f8 t0, t1;                                                               \
        _Pragma("unroll")                                                        \
        for (int q = 0; q < 8; ++q) { t0[q] = (float)h0[q]; t1[q] = (float)h1[q]; } \
        float s = 0.f;                                                           \
        _Pragma("unroll") for (int q = 0; q < 8; ++q) s = fmaf(t0[q], ev0[q], s); \
        _Pragma("unroll") for (int q = 0; q < 8; ++q) s = fmaf(t1[q], ev1[q], s); \
        s = wave_allsum(s);                                                      \
        const float rs = __builtin_amdgcn_rcpf(s);                               \
        _Pragma("unroll") for (int q = 0; q < 8; ++q) ca0[q] = fmaf(t0[q], rs, ca0[q]); \
        _Pragma("unroll") for (int q = 0; q < 8; ++q) ca1[q] = fmaf(t1[q], rs, ca1[q]); \
        if (last) {                                                              \
            _Pragma("unroll")                                                    \
            for (int q = 0; q < 8; ++q) {                                        \
                const float dd = (SHIFT - __logf(t0[q])) * 0.1f;                 \
                qa0[q] = fmaf(t0[q] * dd, rs, qa0[q]);                           \
            }                                                                    \
            _Pragma("unroll")                                                    \
            for (int q = 0; q < 8; ++q) {                                        \
                const float dd = (SHIFT - __logf(t1[q])) * 0.1f;                 \
                qa1[q] = fmaf(t1[q] * dd, rs, qa1[q]);                           \
            }                                                                    \
        }                                                                        \
    }

#define LDS_ROW_PTR(K) ((const h8*)eL[wave * LDS_ROWS + (K)])

// Pin occupancy to EXACTLY 4 waves/EU (16 waves/CU = our 1 block/CU residency,
// which LDS forces anyway). launch_bounds(1024,4) only sets the MINIMUM; the
// backend still targeted 8 waves/EU -> 64-VGPR cap -> spilled the whole state
// (observed: VGPR_Count=64, ~2.7 GB scratch traffic/dispatch). waves_per_eu(4,4)
// raises the VGPR budget to 512/4 = 128.
__global__ void __attribute__((amdgpu_flat_work_group_size(1024, 1024)))
__attribute__((amdgpu_waves_per_eu(4, 4)))
sinkhorn_persist(const float* __restrict__ D, float* __restrict__ Pg,
                 float* __restrict__ Qg, unsigned* __restrict__ ctr,
                 float* __restrict__ out) {
    __shared__ __align__(16) _Float16 eL[NWAVE * LDS_ROWS][NMAT]; // 128 KB
    __shared__ float4 sbuf[1024];                                 // 16 KB
    __shared__ float4 evb4[NMAT / 4];                             // 4 KB (permuted)
    float* evb = (float*)evb4;

    const int b = blockIdx.x;
    const int bb = b >> 3, slab = b & 7;       // batch, row-slab within batch
    const int tid = threadIdx.x;
    const int wave = tid >> 6, lane = tid & 63;
    const size_t rbase = ((size_t)bb << 10) + (slab << 7) + (wave << 3);

    // All per-lane state as NAMED vector variables (no arrays -> no scratch).
    h8 e0a, e0b, e1a, e1b, e2a, e2b, e3a, e3b;   // 4 E rows in regs (32 VGPRs)
    f8 ev0, ev1;                                 // ev at this lane's 16 columns
    f8 ca0, ca1, qa0, qa1;

#pragma unroll 1
    for (int it = 0; it < N_ITERS; ++it) {
        const bool last = (it == N_ITERS - 1);
#pragma unroll
        for (int q = 0; q < 8; ++q) { ca0[q] = 0.f; ca1[q] = 0.f; }
        if (last) {
#pragma unroll
            for (int q = 0; q < 8; ++q) { qa0[q] = 0.f; qa1[q] = 0.f; }
        }

        if (it == 0) {
            // Build phase: read D (only HBM-scale traffic), build fp16 E into
            // regs+LDS, and do iteration 1 (ev == 1) on the fly.
            BUILD_ROW(0, e0a = o0; e0b = o1)
            BUILD_ROW(1, e1a = o0; e1b = o1)
            BUILD_ROW(2, e2a = o0; e2b = o1)
            BUILD_ROW(3, e3a = o0; e3b = o1)
            BUILD_ROW(4, { h8* Er = (h8*)eL[wave * LDS_ROWS + 0]; Er[lane] = o0; Er[lane + 64] = o1; })
            BUILD_ROW(5, { h8* Er = (h8*)eL[wave * LDS_ROWS + 1]; Er[lane] = o0; Er[lane + 64] = o1; })
            BUILD_ROW(6, { h8* Er = (h8*)eL[wave * LDS_ROWS + 2]; Er[lane] = o0; Er[lane + 64] = o1; })
            BUILD_ROW(7, { h8* Er = (h8*)eL[wave * LDS_ROWS + 3]; Er[lane] = o0; Er[lane + 64] = o1; })
        } else {
            // Gather ev for this lane's 16 columns (permuted evb: 16B/lane stride).
            {
                const float4 g0 = evb4[lane];
                const float4 g1 = evb4[64 + lane];
                const float4 g2 = evb4[128 + lane];
                const float4 g3 = evb4[192 + lane];
                ev0[0] = g0.x; ev0[1] = g0.y; ev0[2] = g0.z; ev0[3] = g0.w;
                ev0[4] = g1.x; ev0[5] = g1.y; ev0[6] = g1.z; ev0[7] = g1.w;
                ev1[0] = g2.x; ev1[1] = g2.y; ev1[2] = g2.z; ev1[3] = g2.w;
                ev1[4] = g3.x; ev1[5] = g3.y; ev1[6] = g3.z; ev1[7] = g3.w;
            }
            ITER_ROW(e0a, e0b)
            ITER_ROW(e1a, e1b)
            ITER_ROW(e2a, e2b)
            ITER_ROW(e3a, e3b)
            ITER_ROW(LDS_ROW_PTR(0)[lane], LDS_ROW_PTR(0)[lane + 64])
            ITER_ROW(LDS_ROW_PTR(1)[lane], LDS_ROW_PTR(1)[lane + 64])
            ITER_ROW(LDS_ROW_PTR(2)[lane], LDS_ROW_PTR(2)[lane + 64])
            ITER_ROW(LDS_ROW_PTR(3)[lane], LDS_ROW_PTR(3)[lane + 64])
        }

        // Block-level column reduction -> one 4 KB partial per block.
        const int par = it & 1;   // parity double-buffer (no 2nd barrier needed)
        const float cs = stage_colsum(ca0, ca1, sbuf, wave, lane, tid);
        Pg[((par * NBLK + b) << 10) + tid] = cs;
        if (last) {
            const float qs = stage_colsum(qa0, qa1, sbuf, wave, lane, tid);
            Qg[(b << 10) + tid] = qs;
            if (b == 0 && tid == 0) out[0] = 0.f;   // arm final atomics
        }

        grid_barrier(&ctr[it], tid);

        if (!last) {
            // Redundant per-block ev: gather this batch's 8 partials.
            const float* Pb = Pg + ((par * NBLK + (bb << 3)) << 10) + tid;
            float s8 = 0.f;
#pragma unroll
            for (int j = 0; j < 8; ++j) s8 += Pb[j << 10];
            const float evv = 1.0f / s8;
            const int rem = tid & 511, lt = rem >> 3, ut = rem & 7;
            const int ht = ((tid >> 9) << 1) + (ut >> 2), rt = ut & 3;
            evb[(((ht << 6) + lt) << 2) + rt] = evv;
            __syncthreads();               // evb ready for next iteration
        } else if (slab == 0) {
            // loss = mean_b sum_m (sum_j Q[j][m]) / (sum_j P[j][m])
            const float* Pb = Pg + ((par * NBLK + (bb << 3)) << 10) + tid;
            const float* Qb = Qg + (((bb << 3)) << 10) + tid;
            float s8 = 0.f, q8 = 0.f;
#pragma unroll
            for (int j = 0; j < 8; ++j) { s8 += Pb[j << 10]; q8 += Qb[j << 10]; }
            float c = q8 / s8;
            c = wave_allsum(c);
            if (lane == 0) ((float*)sbuf)[wave] = c;
            __syncthreads();
            if (tid == 0) {
                float tot = 0.f;
#pragma unroll
                for (int w = 0; w < NWAVE; ++w) tot += ((float*)sbuf)[w];
                atomicAdd(out, tot * (1.0f / (float)BATCH));
            }
        }
    }
}

extern "C" void kernel_launch(void* const* d_in, const int* in_sizes, int n_in,
                              void* d_out, int out_size, void* d_ws, size_t ws_size,
                              hipStream_t stream) {
    const float* D = (const float*)d_in[0];
    float* out = (float*)d_out;

    unsigned* ctr = (unsigned*)d_ws;                    // 64 slots (zeroed below)
    float* Pg = (float*)((char*)d_ws + 1024);           // [2][256][1024] f32 = 2 MB
    float* Qg = Pg + 2 * NBLK * NMAT;                   // [256][1024] f32 = 1 MB

    init_ctr<<<1, 64, 0, stream>>>(ctr);
    sinkhorn_persist<<<NBLK, NWAVE * 64, 0, stream>>>(D, Pg, Qg, ctr, out);
}